// Round 11
// baseline (164.291 us; speedup 1.0000x reference)
//
#include <hip/hip_runtime.h>
#include <math.h>

#define BB 2
#define NN 2048
#define KK 30
#define DD 128
#define HH 4
#define PQ_ 8
#define PV_ 4
#define TM 16      // nodes per MFMA block (proj + tail)

#define INV3C    0.05103103630798288f   // sqrt(1/(3*128))
#define INV3     0.5773502691896258f    // sqrt(1/3)
#define PT_SCALE 0.09622504486493764f   // sqrt(1/108)

typedef __attribute__((ext_vector_type(8))) short short8;
typedef __attribute__((ext_vector_type(4))) float f32x4;
typedef unsigned short ushort_t;

__device__ __forceinline__ ushort_t f2bf(float f) {
    unsigned u = __float_as_uint(f);
    unsigned r = u + 0x7FFFu + ((u >> 16) & 1u);   // RNE
    return (ushort_t)(r >> 16);
}
__device__ __forceinline__ float bf2f(ushort_t u) {
    return __uint_as_float(((unsigned)u) << 16);
}

// ---- weight prep: bf16 transposed weights for all MFMA GEMMs ----
__global__ __launch_bounds__(256) void prep_kernel(
    const float* __restrict__ Wout, const float* __restrict__ Wm1,
    const float* __restrict__ Wm2,
    const float* __restrict__ Wq, const float* __restrict__ Wkv,
    const float* __restrict__ Wqp, const float* __restrict__ Wkvp,
    ushort_t* __restrict__ WoutT, ushort_t* __restrict__ Wm1T,
    ushort_t* __restrict__ Wm2T, ushort_t* __restrict__ WprojT)
{
    const int stride = gridDim.x * blockDim.x;
    const int t0 = blockIdx.x * blockDim.x + threadIdx.x;
    for (int idx = t0; idx < 128 * 1088; idx += stride) {
        int n = idx / 1088, k = idx - n * 1088;
        WoutT[idx] = f2bf(Wout[(size_t)k * 128 + n]);
    }
    for (int idx = t0; idx < 512 * 128; idx += stride) {
        int n = idx >> 7, k = idx & 127;
        Wm1T[idx] = f2bf(Wm1[(size_t)k * 512 + n]);
    }
    for (int idx = t0; idx < 128 * 512; idx += stride) {
        int n = idx >> 9, k = idx & 511;
        Wm2T[idx] = f2bf(Wm2[(size_t)k * 128 + n]);
    }
    // fused proj weight: n<512 q | 512..1536 kv | 1536..1632 qp | 1632..1776 kvp | pad
    for (int idx = t0; idx < 1792 * 128; idx += stride) {
        int n = idx >> 7, k = idx & 127;
        float v;
        if (n < 512)       v = Wq[(size_t)k * 512 + n];
        else if (n < 1536) v = Wkv[(size_t)k * 1024 + (n - 512)];
        else if (n < 1632) v = Wqp[k * 96 + (n - 1536)];
        else if (n < 1776) v = Wkvp[k * 144 + (n - 1632)];
        else               v = 0.f;
        WprojT[idx] = f2bf(v);
    }
}

// ---- proj: MFMA GEMM X[16x128]bf16 @ WprojT ----
__global__ __launch_bounds__(512) void proj_kernel(
    const float* __restrict__ hV, const float* __restrict__ R, const float* __restrict__ tvec,
    const ushort_t* __restrict__ WT,
    const float* __restrict__ bq, const float* __restrict__ bkv,
    const float* __restrict__ bqp, const float* __restrict__ bkvp,
    ushort_t* __restrict__ qb, ushort_t* __restrict__ kb, ushort_t* __restrict__ vb,
    float* __restrict__ qpts, float* __restrict__ kpts, float* __restrict__ vpts)
{
    const int node0 = (blockIdx.x >> 1) * TM;
    const int half  = blockIdx.x & 1;
    const int tid = threadIdx.x;
    const int w = tid >> 6, l = tid & 63, lr = l & 15, lk = l >> 4;

    __shared__ ushort_t s_A[TM][128];    // 4 KB bf16 A tile
    __shared__ float s_qp[TM][96];       // 6 KB
    __shared__ float s_kvp[TM][144];     // 9 KB

    {
        int i = tid * 4; int r = i >> 7, c = i & 127;
        float4 x = *(const float4*)&hV[(size_t)(node0 + r) * DD + c];
        s_A[r][c + 0] = f2bf(x.x); s_A[r][c + 1] = f2bf(x.y);
        s_A[r][c + 2] = f2bf(x.z); s_A[r][c + 3] = f2bf(x.w);
    }
    __syncthreads();

    const ushort_t* Ab = &s_A[lr][lk * 8];
    for (int t = 0; t < 7; ++t) {
        const int tile = half * 56 + w * 7 + t;
        const int n = tile * 16 + lr;
        f32x4 acc = {0.f, 0.f, 0.f, 0.f};
        const ushort_t* Bb = WT + (size_t)n * 128 + lk * 8;
        #pragma unroll
        for (int ks = 0; ks < 4; ++ks) {
            short8 a = *(const short8*)(Ab + ks * 32);
            short8 bfr = *(const short8*)(Bb + ks * 32);
            acc = __builtin_amdgcn_mfma_f32_16x16x32_bf16(a, bfr, acc, 0, 0, 0);
        }
        if (n < 512) {
            float bias = bq[n];
            #pragma unroll
            for (int i = 0; i < 4; ++i)
                qb[(size_t)(node0 + lk * 4 + i) * 512 + n] = f2bf(acc[i] + bias);
        } else if (n < 1536) {
            int n2 = n - 512;
            float bias = bkv[n2];
            int hh = n2 >> 8, wcol = n2 & 255;
            ushort_t* base = (wcol < 128) ? kb : vb;
            int off = hh * DD + (wcol & 127);
            #pragma unroll
            for (int i = 0; i < 4; ++i)
                base[(size_t)(node0 + lk * 4 + i) * 512 + off] = f2bf(acc[i] + bias);
        } else if (n < 1632) {
            int c = n - 1536;
            float bias = bqp[c];
            #pragma unroll
            for (int i = 0; i < 4; ++i) s_qp[lk * 4 + i][c] = acc[i] + bias;
        } else if (n < 1776) {
            int c = n - 1632;
            float bias = bkvp[c];
            #pragma unroll
            for (int i = 0; i < 4; ++i) s_kvp[lk * 4 + i][c] = acc[i] + bias;
        }
    }
    __syncthreads();

    if (half == 1) {
        for (int idx = tid; idx < TM * 96; idx += 512) {
            int r = idx / 96, u = idx % 96;
            int j = u / 3, d = u % 3;
            int node = node0 + r;
            float acc = tvec[node * 3 + d];
            #pragma unroll
            for (int y = 0; y < 3; ++y)
                acc = fmaf(R[node * 9 + d * 3 + y], s_qp[r][y * 32 + j], acc);
            qpts[(size_t)node * 96 + j * 3 + d] = acc;
        }
        for (int idx = tid; idx < TM * 144; idx += 512) {
            int r = idx / 144, u = idx % 144;
            int jj = u / 3, d = u % 3;
            int node = node0 + r;
            float acc = tvec[node * 3 + d];
            #pragma unroll
            for (int y = 0; y < 3; ++y)
                acc = fmaf(R[node * 9 + d * 3 + y], s_kvp[r][y * 48 + jj], acc);
            int hh = jj / 12, pp = jj % 12;
            if (pp < PQ_) kpts[(size_t)node * 96 + (hh * PQ_ + pp) * 3 + d] = acc;
            else          vpts[(size_t)node * 64 + (hh * PV_ + (pp - PQ_)) * 4 + d] = acc;  // padded [16][4]
        }
    }
}

// ---- attn core: wide-load restructure. hE staged cooperatively to bf16 LDS
// first; logits 4 k/iter via 16-lane groups (short8 loads); o/o_pair/o_pt in
// one loop with 4 k in flight and 16B gathers. ----
__global__ __launch_bounds__(256, 6) void attn_kernel(
    const float* __restrict__ hE, const int* __restrict__ Eidx,
    const float* __restrict__ R, const float* __restrict__ tvec,
    const float* __restrict__ mask_att,
    const float* __restrict__ Wb, const float* __restrict__ bb,
    const float* __restrict__ head_w,
    const ushort_t* __restrict__ qb, const ushort_t* __restrict__ kb,
    const ushort_t* __restrict__ vb,
    const float* __restrict__ qpts, const float* __restrict__ kpts, const float* __restrict__ vpts,
    ushort_t* __restrict__ catb)
{
    const int node = blockIdx.x;
    const int b = node >> 11;
    const int tid = threadIdx.x;
    const int lane = tid & 63;
    const int wv = tid >> 6;
    const int l16 = lane & 15;
    const int g4 = lane >> 4;

    __shared__ ushort_t s_hEb[KK * DD];   // 7680 B
    __shared__ float s_cat[1088];
    __shared__ float s_qp[96];
    __shared__ float s_p[HH][32];
    __shared__ int   s_j[32];
    __shared__ float s_mask[32];
    __shared__ float s_opt[48];

    if (tid < 96) s_qp[tid] = qpts[(size_t)node * 96 + tid];
    if (tid < KK) {
        s_j[tid] = Eidx[(size_t)node * KK + tid];
        s_mask[tid] = 100000.0f * (mask_att[(size_t)node * KK + tid] - 1.0f);
    }
    // ---- cooperative hE stage: wave wv rows k = wv + 4i, float2/lane ----
    const float* hE_node = hE + (size_t)node * (KK * DD);
    #pragma unroll
    for (int i = 0; i < 8; ++i) {
        const int k = wv + i * 4;
        if (k < KK) {
            float2 hv2 = *(const float2*)&hE_node[k * DD + lane * 2];
            unsigned pk = ((unsigned)f2bf(hv2.y) << 16) | (unsigned)f2bf(hv2.x);
            *(unsigned*)&s_hEb[k * DD + lane * 2] = pk;
        }
    }
    __syncthreads();

    const int h = wv;
    // per-lane fragments: 8 contiguous cols l16*8..+7
    float qf[8], wbv[8];
    {
        short8 q8 = *(const short8*)&qb[(size_t)node * 512 + h * DD + l16 * 8];
        #pragma unroll
        for (int j = 0; j < 8; ++j) qf[j] = bf2f((ushort_t)q8[j]);
    }
    #pragma unroll
    for (int j = 0; j < 8; ++j) wbv[j] = Wb[(l16 * 8 + j) * HH + h];
    const float cpt = -0.5f * PT_SCALE * log1pf(expf(head_w[h]));
    const float bbh = INV3 * bb[h];
    float2 qp2 = make_float2(0.f, 0.f);
    if (l16 < 12) qp2 = *(const float2*)&s_qp[h * 24 + 2 * l16];

    // ---- logits: 4 k per iteration (one per 16-lane group) ----
    #pragma unroll
    for (int i = 0; i < 8; ++i) {
        const int k = i * 4 + g4;
        if (k < KK) {
            size_t jb = (size_t)(b * NN + s_j[k]);
            short8 k8 = *(const short8*)&kb[jb * 512 + h * DD + l16 * 8];
            short8 e8 = *(const short8*)&s_hEb[k * DD + l16 * 8];
            float s = 0.f, t = 0.f;
            #pragma unroll
            for (int j = 0; j < 8; ++j) {
                s = fmaf(qf[j], bf2f((ushort_t)k8[j]), s);
                t = fmaf(wbv[j], bf2f((ushort_t)e8[j]), t);
            }
            float ptc = 0.f;
            if (l16 < 12) {
                float2 kp2 = *(const float2*)&kpts[jb * 96 + h * 24 + 2 * l16];
                float d0 = qp2.x - kp2.x, d1 = qp2.y - kp2.y;
                ptc = d0 * d0 + d1 * d1;
            }
            float val = INV3C * s + INV3 * t + cpt * ptc;
            #pragma unroll
            for (int off = 8; off; off >>= 1) val += __shfl_down(val, off, 16);
            if (l16 == 0) s_p[h][k] = val + bbh + s_mask[k];
        }
    }
    __syncthreads();

    // ---- softmax over k (wave-local) ----
    {
        float v = (lane < KK) ? s_p[h][lane] : -INFINITY;
        float m = v;
        #pragma unroll
        for (int off = 16; off; off >>= 1) m = fmaxf(m, __shfl_down(m, off));
        m = __shfl(m, 0);
        float e = (lane < KK) ? expf(v - m) : 0.f;
        float s = e;
        #pragma unroll
        for (int off = 16; off; off >>= 1) s += __shfl_down(s, off);
        s = __shfl(s, 0);
        if (lane < KK) s_p[h][lane] = e / s;
    }
    __syncthreads();

    // ---- o + o_pair + o_pt, 4 k in flight (one per 16-lane group) ----
    {
        float a[8], bp[8];
        #pragma unroll
        for (int j = 0; j < 8; ++j) { a[j] = 0.f; bp[j] = 0.f; }
        float p0 = 0.f, p1 = 0.f, p2 = 0.f;
        const int pj = h * PV_ + l16;              // point index (l16<4)
        #pragma unroll
        for (int i = 0; i < 8; ++i) {
            const int kx = i * 4 + g4;
            if (kx < KK) {
                size_t jb = (size_t)(b * NN + s_j[kx]);
                short8 v8 = *(const short8*)&vb[jb * 512 + h * DD + l16 * 8];
                short8 e8 = *(const short8*)&s_hEb[kx * DD + l16 * 8];
                float p = s_p[h][kx];
                #pragma unroll
                for (int j = 0; j < 8; ++j) {
                    a[j]  = fmaf(p, bf2f((ushort_t)v8[j]), a[j]);
                    bp[j] = fmaf(p, bf2f((ushort_t)e8[j]), bp[j]);
                }
                if (l16 < 4) {
                    float4 vp4 = *(const float4*)&vpts[jb * 64 + pj * 4];
                    p0 = fmaf(p, vp4.x, p0);
                    p1 = fmaf(p, vp4.y, p1);
                    p2 = fmaf(p, vp4.z, p2);
                }
            }
        }
        // cross-group combine (4 groups -> group 0)
        #pragma unroll
        for (int j = 0; j < 8; ++j) {
            a[j]  += __shfl_down(a[j], 32);  a[j]  += __shfl_down(a[j], 16);
            bp[j] += __shfl_down(bp[j], 32); bp[j] += __shfl_down(bp[j], 16);
        }
        p0 += __shfl_down(p0, 32); p0 += __shfl_down(p0, 16);
        p1 += __shfl_down(p1, 32); p1 += __shfl_down(p1, 16);
        p2 += __shfl_down(p2, 32); p2 += __shfl_down(p2, 16);
        if (g4 == 0) {
            #pragma unroll
            for (int j = 0; j < 8; ++j) {
                s_cat[h * DD + l16 * 8 + j]       = a[j];
                s_cat[576 + h * DD + l16 * 8 + j] = bp[j];
            }
            if (l16 < 4) {
                s_opt[pj * 3 + 0] = p0;
                s_opt[pj * 3 + 1] = p1;
                s_opt[pj * 3 + 2] = p2;
            }
        }
    }
    __syncthreads();

    // ---- inverse rigid + norm (16 points) ----
    if (tid < 16) {
        int jj = tid;
        float g0 = s_opt[jj * 3 + 0] - tvec[node * 3 + 0];
        float g1 = s_opt[jj * 3 + 1] - tvec[node * 3 + 1];
        float g2 = s_opt[jj * 3 + 2] - tvec[node * 3 + 2];
        float l0 = R[node * 9 + 0] * g0 + R[node * 9 + 3] * g1 + R[node * 9 + 6] * g2;
        float l1 = R[node * 9 + 1] * g0 + R[node * 9 + 4] * g1 + R[node * 9 + 7] * g2;
        float l2 = R[node * 9 + 2] * g0 + R[node * 9 + 5] * g1 + R[node * 9 + 8] * g2;
        s_cat[512 + 0 * 16 + jj] = l0;
        s_cat[512 + 1 * 16 + jj] = l1;
        s_cat[512 + 2 * 16 + jj] = l2;
        s_cat[560 + jj] = sqrtf(l0 * l0 + l1 * l1 + l2 * l2 + 1e-8f);
    }
    __syncthreads();

    for (int i = tid; i < 1088; i += 256)
        catb[(size_t)node * 1088 + i] = f2bf(s_cat[i]);
}

// ---- tail: MFMA GEMMs. 16 nodes/block, 512 threads (8 waves), grid 256. ----
__global__ __launch_bounds__(512) void tail_kernel(
    const float* __restrict__ hV, const float* __restrict__ maskV,
    const ushort_t* __restrict__ catb,
    const ushort_t* __restrict__ WoutT, const float* __restrict__ bout,
    const float* __restrict__ ln0w, const float* __restrict__ ln0b,
    const float* __restrict__ ln1w, const float* __restrict__ ln1b,
    const ushort_t* __restrict__ Wm1T, const float* __restrict__ bm1,
    const ushort_t* __restrict__ Wm2T, const float* __restrict__ bm2,
    float* __restrict__ out)
{
    const int node0 = blockIdx.x * TM;
    const int tid = threadIdx.x;
    const int w  = tid >> 6;
    const int l  = tid & 63;
    const int lr = l & 15;
    const int lk = l >> 4;

    __shared__ float    s_x[TM][DD];
    __shared__ float    s_hv[TM][DD];
    __shared__ ushort_t s_hvb[TM][136];
    __shared__ ushort_t s_m1[TM][520];
    __shared__ float    s_rs[TM][16];
    __shared__ float    s_rq[TM][16];
    __shared__ float    s_stat[TM][2];

    // ---- GEMM1: s = cat[16x1088] @ Wout[1088x128]
    {
        f32x4 acc = {0.f, 0.f, 0.f, 0.f};
        const ushort_t* Ab = catb + (size_t)(node0 + lr) * 1088 + lk * 8;
        const ushort_t* Bb = WoutT + (size_t)(w * 16 + lr) * 1088 + lk * 8;
        #pragma unroll 2
        for (int ks = 0; ks < 34; ++ks) {
            short8 a = *(const short8*)(Ab + ks * 32);
            short8 bfr = *(const short8*)(Bb + ks * 32);
            acc = __builtin_amdgcn_mfma_f32_16x16x32_bf16(a, bfr, acc, 0, 0, 0);
        }
        #pragma unroll
        for (int i = 0; i < 4; ++i)
            s_x[lk * 4 + i][w * 16 + lr] = acc[i];
    }
    __syncthreads();

    // ---- bias + residual + LN0 ----
    if (tid < 256) {
        int r = tid >> 4, sg = tid & 15;
        float ss = 0.f, sq = 0.f;
        #pragma unroll
        for (int j = 0; j < 8; ++j) {
            int cc = sg * 8 + j;
            float x = s_x[r][cc] + bout[cc] + hV[(size_t)(node0 + r) * DD + cc];
            s_x[r][cc] = x;
            ss += x; sq += x * x;
        }
        s_rs[r][sg] = ss; s_rq[r][sg] = sq;
    }
    __syncthreads();
    if (tid < TM) {
        float ss = 0.f, sq = 0.f;
        #pragma unroll
        for (int sg = 0; sg < 16; ++sg) { ss += s_rs[tid][sg]; sq += s_rq[tid][sg]; }
        float mu = ss / 128.f;
        s_stat[tid][0] = mu;
        s_stat[tid][1] = rsqrtf(sq / 128.f - mu * mu + 1e-5f);
    }
    __syncthreads();
    {
        int idx = tid * 4;
        int r = idx >> 7, cc = idx & 127;
        float mu = s_stat[r][0], rstd = s_stat[r][1];
        #pragma unroll
        for (int j = 0; j < 4; ++j) {
            float hvv = (s_x[r][cc + j] - mu) * rstd * ln0w[cc + j] + ln0b[cc + j];
            s_hv[r][cc + j] = hvv;
            s_hvb[r][cc + j] = f2bf(hvv);
        }
    }
    __syncthreads();

    // ---- GEMM2: m1 = hv[16x128] @ Wm1[128x512], ReLU ----
    {
        const ushort_t* Ab = &s_hvb[lr][lk * 8];
        #pragma unroll
        for (int t = 0; t < 4; ++t) {
            int n0 = w * 64 + t * 16;
            f32x4 acc = {0.f, 0.f, 0.f, 0.f};
            const ushort_t* Bb = Wm1T + (size_t)(n0 + lr) * 128 + lk * 8;
            #pragma unroll
            for (int ks = 0; ks < 4; ++ks) {
                short8 a = *(const short8*)(Ab + ks * 32);
                short8 bfr = *(const short8*)(Bb + ks * 32);
                acc = __builtin_amdgcn_mfma_f32_16x16x32_bf16(a, bfr, acc, 0, 0, 0);
            }
            int n = n0 + lr;
            float bm = bm1[n];
            #pragma unroll
            for (int i = 0; i < 4; ++i)
                s_m1[lk * 4 + i][n] = f2bf(fmaxf(acc[i] + bm, 0.f));
        }
    }
    __syncthreads();

    // ---- GEMM3: m = m1[16x512] @ Wm2[512x128] ----
    {
        f32x4 acc = {0.f, 0.f, 0.f, 0.f};
        const ushort_t* Ab = &s_m1[lr][lk * 8];
        const ushort_t* Bb = Wm2T + (size_t)(w * 16 + lr) * 512 + lk * 8;
        #pragma unroll 4
        for (int ks = 0; ks < 16; ++ks) {
            short8 a = *(const short8*)(Ab + ks * 32);
            short8 bfr = *(const short8*)(Bb + ks * 32);
            acc = __builtin_amdgcn_mfma_f32_16x16x32_bf16(a, bfr, acc, 0, 0, 0);
        }
        #pragma unroll
        for (int i = 0; i < 4; ++i)
            s_x[lk * 4 + i][w * 16 + lr] = acc[i];
    }
    __syncthreads();

    // ---- bm2 + residual + LN1 ----
    if (tid < 256) {
        int r = tid >> 4, sg = tid & 15;
        float ss = 0.f, sq = 0.f;
        #pragma unroll
        for (int j = 0; j < 8; ++j) {
            int cc = sg * 8 + j;
            float x = s_x[r][cc] + bm2[cc] + s_hv[r][cc];
            s_x[r][cc] = x;
            ss += x; sq += x * x;
        }
        s_rs[r][sg] = ss; s_rq[r][sg] = sq;
    }
    __syncthreads();
    if (tid < TM) {
        float ss = 0.f, sq = 0.f;
        #pragma unroll
        for (int sg = 0; sg < 16; ++sg) { ss += s_rs[tid][sg]; sq += s_rq[tid][sg]; }
        float mu = ss / 128.f;
        s_stat[tid][0] = mu;
        s_stat[tid][1] = rsqrtf(sq / 128.f - mu * mu + 1e-5f);
    }
    __syncthreads();
    {
        int idx = tid * 4;
        int r = idx >> 7, cc = idx & 127;
        float mu = s_stat[r][0], rstd = s_stat[r][1];
        float mk = maskV[node0 + r];
        float4 o;
        o.x = ((s_x[r][cc + 0] - mu) * rstd * ln1w[cc + 0] + ln1b[cc + 0]) * mk;
        o.y = ((s_x[r][cc + 1] - mu) * rstd * ln1w[cc + 1] + ln1b[cc + 1]) * mk;
        o.z = ((s_x[r][cc + 2] - mu) * rstd * ln1w[cc + 2] + ln1b[cc + 2]) * mk;
        o.w = ((s_x[r][cc + 3] - mu) * rstd * ln1w[cc + 3] + ln1b[cc + 3]) * mk;
        *(float4*)&out[(size_t)(node0 + r) * DD + cc] = o;
    }
}

extern "C" void kernel_launch(void* const* d_in, const int* in_sizes, int n_in,
                              void* d_out, int out_size, void* d_ws, size_t ws_size,
                              hipStream_t stream)
{
    const float* hV      = (const float*)d_in[0];
    const float* hE      = (const float*)d_in[1];
    const int*   Eidx    = (const int*)  d_in[2];
    const float* R       = (const float*)d_in[3];
    const float* tvec    = (const float*)d_in[4];
    const float* mask_at = (const float*)d_in[5];
    const float* maskV   = (const float*)d_in[6];
    const float* Wq      = (const float*)d_in[7];
    const float* bq      = (const float*)d_in[8];
    const float* Wkv     = (const float*)d_in[9];
    const float* bkv     = (const float*)d_in[10];
    const float* Wqp     = (const float*)d_in[11];
    const float* bqp     = (const float*)d_in[12];
    const float* Wkvp    = (const float*)d_in[13];
    const float* bkvp    = (const float*)d_in[14];
    const float* Wb      = (const float*)d_in[15];
    const float* bb      = (const float*)d_in[16];
    const float* hw      = (const float*)d_in[17];
    const float* Wout    = (const float*)d_in[18];
    const float* bout    = (const float*)d_in[19];
    const float* ln0w    = (const float*)d_in[20];
    const float* ln0b    = (const float*)d_in[21];
    const float* ln1w    = (const float*)d_in[22];
    const float* ln1b    = (const float*)d_in[23];
    const float* Wm1     = (const float*)d_in[24];
    const float* bm1     = (const float*)d_in[25];
    const float* Wm2     = (const float*)d_in[26];
    const float* bm2     = (const float*)d_in[27];

    const size_t nodes = (size_t)BB * NN;
    ushort_t* qb     = (ushort_t*)d_ws;                 // nodes*512 bf16
    ushort_t* kb     = qb + nodes * 512;
    ushort_t* vb     = kb + nodes * 512;
    ushort_t* catb   = vb + nodes * 512;                // nodes*1088
    ushort_t* WoutT  = catb + nodes * 1088;
    ushort_t* Wm1T   = WoutT + 128 * 1088;
    ushort_t* Wm2T   = Wm1T + 512 * 128;
    ushort_t* WprojT = Wm2T + 128 * 512;                // 1792*128
    float* qpts = (float*)(WprojT + 1792 * 128);
    float* kpts = qpts + nodes * 96;
    float* vpts = kpts + nodes * 96;                    // padded [node][16][4]

    prep_kernel<<<256, 256, 0, stream>>>(Wout, Wm1, Wm2, Wq, Wkv, Wqp, Wkvp,
                                         WoutT, Wm1T, Wm2T, WprojT);

    proj_kernel<<<(int)(nodes / TM) * 2, 512, 0, stream>>>(
        hV, R, tvec, WprojT, bq, bkv, bqp, bkvp,
        qb, kb, vb, qpts, kpts, vpts);

    attn_kernel<<<(int)nodes, 256, 0, stream>>>(
        hE, Eidx, R, tvec, mask_at,
        Wb, bb, hw,
        qb, kb, vb, qpts, kpts, vpts, catb);

    tail_kernel<<<(int)(nodes / TM), 512, 0, stream>>>(
        hV, maskV, catb,
        WoutT, bout, ln0w, ln0b, ln1w, ln1b,
        Wm1T, bm1, Wm2T, bm2, (float*)d_out);
}

// Round 12
// 106.688 us; speedup vs baseline: 1.5399x; 1.5399x over previous
//
#include <hip/hip_runtime.h>
#include <math.h>

#define BB 2
#define NN 2048
#define KK 30
#define DD 128
#define HH 4
#define PQ_ 8
#define PV_ 4
#define TM 16      // nodes per MFMA block (proj + tail)

#define INV3C    0.05103103630798288f   // sqrt(1/(3*128))
#define INV3     0.5773502691896258f    // sqrt(1/3)
#define PT_SCALE 0.09622504486493764f   // sqrt(1/108)

typedef __attribute__((ext_vector_type(8))) short short8;
typedef __attribute__((ext_vector_type(4))) float f32x4;
typedef unsigned short ushort_t;

__device__ __forceinline__ ushort_t f2bf(float f) {
    unsigned u = __float_as_uint(f);
    unsigned r = u + 0x7FFFu + ((u >> 16) & 1u);   // RNE
    return (ushort_t)(r >> 16);
}
__device__ __forceinline__ float bf2f(ushort_t u) {
    return __uint_as_float(((unsigned)u) << 16);
}
__device__ __forceinline__ float bflo(unsigned u) {
    return __uint_as_float(u << 16);
}
__device__ __forceinline__ float bfhi(unsigned u) {
    return __uint_as_float(u & 0xffff0000u);
}

// ---- weight prep: bf16 transposed weights for all MFMA GEMMs ----
__global__ __launch_bounds__(256) void prep_kernel(
    const float* __restrict__ Wout, const float* __restrict__ Wm1,
    const float* __restrict__ Wm2,
    const float* __restrict__ Wq, const float* __restrict__ Wkv,
    const float* __restrict__ Wqp, const float* __restrict__ Wkvp,
    ushort_t* __restrict__ WoutT, ushort_t* __restrict__ Wm1T,
    ushort_t* __restrict__ Wm2T, ushort_t* __restrict__ WprojT)
{
    const int stride = gridDim.x * blockDim.x;
    const int t0 = blockIdx.x * blockDim.x + threadIdx.x;
    for (int idx = t0; idx < 128 * 1088; idx += stride) {
        int n = idx / 1088, k = idx - n * 1088;
        WoutT[idx] = f2bf(Wout[(size_t)k * 128 + n]);
    }
    for (int idx = t0; idx < 512 * 128; idx += stride) {
        int n = idx >> 7, k = idx & 127;
        Wm1T[idx] = f2bf(Wm1[(size_t)k * 512 + n]);
    }
    for (int idx = t0; idx < 128 * 512; idx += stride) {
        int n = idx >> 9, k = idx & 511;
        Wm2T[idx] = f2bf(Wm2[(size_t)k * 128 + n]);
    }
    // fused proj weight: n<512 q | 512..1536 kv | 1536..1632 qp | 1632..1776 kvp | pad
    for (int idx = t0; idx < 1792 * 128; idx += stride) {
        int n = idx >> 7, k = idx & 127;
        float v;
        if (n < 512)       v = Wq[(size_t)k * 512 + n];
        else if (n < 1536) v = Wkv[(size_t)k * 1024 + (n - 512)];
        else if (n < 1632) v = Wqp[k * 96 + (n - 1536)];
        else if (n < 1776) v = Wkvp[k * 144 + (n - 1632)];
        else               v = 0.f;
        WprojT[idx] = f2bf(v);
    }
}

// ---- proj: MFMA GEMM X[16x128]bf16 @ WprojT ----
__global__ __launch_bounds__(512) void proj_kernel(
    const float* __restrict__ hV, const float* __restrict__ R, const float* __restrict__ tvec,
    const ushort_t* __restrict__ WT,
    const float* __restrict__ bq, const float* __restrict__ bkv,
    const float* __restrict__ bqp, const float* __restrict__ bkvp,
    ushort_t* __restrict__ qb, ushort_t* __restrict__ kb, ushort_t* __restrict__ vb,
    float* __restrict__ qpts, float* __restrict__ kpts, float* __restrict__ vpts)
{
    const int node0 = (blockIdx.x >> 1) * TM;
    const int half  = blockIdx.x & 1;
    const int tid = threadIdx.x;
    const int w = tid >> 6, l = tid & 63, lr = l & 15, lk = l >> 4;

    __shared__ ushort_t s_A[TM][128];    // 4 KB bf16 A tile
    __shared__ float s_qp[TM][96];       // 6 KB
    __shared__ float s_kvp[TM][144];     // 9 KB

    {
        int i = tid * 4; int r = i >> 7, c = i & 127;
        float4 x = *(const float4*)&hV[(size_t)(node0 + r) * DD + c];
        s_A[r][c + 0] = f2bf(x.x); s_A[r][c + 1] = f2bf(x.y);
        s_A[r][c + 2] = f2bf(x.z); s_A[r][c + 3] = f2bf(x.w);
    }
    __syncthreads();

    const ushort_t* Ab = &s_A[lr][lk * 8];
    for (int t = 0; t < 7; ++t) {
        const int tile = half * 56 + w * 7 + t;
        const int n = tile * 16 + lr;
        f32x4 acc = {0.f, 0.f, 0.f, 0.f};
        const ushort_t* Bb = WT + (size_t)n * 128 + lk * 8;
        #pragma unroll
        for (int ks = 0; ks < 4; ++ks) {
            short8 a = *(const short8*)(Ab + ks * 32);
            short8 bfr = *(const short8*)(Bb + ks * 32);
            acc = __builtin_amdgcn_mfma_f32_16x16x32_bf16(a, bfr, acc, 0, 0, 0);
        }
        if (n < 512) {
            float bias = bq[n];
            #pragma unroll
            for (int i = 0; i < 4; ++i)
                qb[(size_t)(node0 + lk * 4 + i) * 512 + n] = f2bf(acc[i] + bias);
        } else if (n < 1536) {
            int n2 = n - 512;
            float bias = bkv[n2];
            int hh = n2 >> 8, wcol = n2 & 255;
            ushort_t* base = (wcol < 128) ? kb : vb;
            int off = hh * DD + (wcol & 127);
            #pragma unroll
            for (int i = 0; i < 4; ++i)
                base[(size_t)(node0 + lk * 4 + i) * 512 + off] = f2bf(acc[i] + bias);
        } else if (n < 1632) {
            int c = n - 1536;
            float bias = bqp[c];
            #pragma unroll
            for (int i = 0; i < 4; ++i) s_qp[lk * 4 + i][c] = acc[i] + bias;
        } else if (n < 1776) {
            int c = n - 1632;
            float bias = bkvp[c];
            #pragma unroll
            for (int i = 0; i < 4; ++i) s_kvp[lk * 4 + i][c] = acc[i] + bias;
        }
    }
    __syncthreads();

    if (half == 1) {
        for (int idx = tid; idx < TM * 96; idx += 512) {
            int r = idx / 96, u = idx % 96;
            int j = u / 3, d = u % 3;
            int node = node0 + r;
            float acc = tvec[node * 3 + d];
            #pragma unroll
            for (int y = 0; y < 3; ++y)
                acc = fmaf(R[node * 9 + d * 3 + y], s_qp[r][y * 32 + j], acc);
            qpts[(size_t)node * 96 + j * 3 + d] = acc;
        }
        for (int idx = tid; idx < TM * 144; idx += 512) {
            int r = idx / 144, u = idx % 144;
            int jj = u / 3, d = u % 3;
            int node = node0 + r;
            float acc = tvec[node * 3 + d];
            #pragma unroll
            for (int y = 0; y < 3; ++y)
                acc = fmaf(R[node * 9 + d * 3 + y], s_kvp[r][y * 48 + jj], acc);
            int hh = jj / 12, pp = jj % 12;
            if (pp < PQ_) kpts[(size_t)node * 96 + (hh * PQ_ + pp) * 3 + d] = acc;
            else          vpts[(size_t)node * 48 + (hh * PV_ + (pp - PQ_)) * 3 + d] = acc;
        }
    }
}

// ---- attn core: r10 structure + spill-proof chunked load blocks.
// Named scalars only; no arrays, no conditionally-initialized values. ----
__global__ __launch_bounds__(256, 6) void attn_kernel(
    const float* __restrict__ hE, const int* __restrict__ Eidx,
    const float* __restrict__ R, const float* __restrict__ tvec,
    const float* __restrict__ mask_att,
    const float* __restrict__ Wb, const float* __restrict__ bb,
    const float* __restrict__ head_w,
    const ushort_t* __restrict__ qb, const ushort_t* __restrict__ kb,
    const ushort_t* __restrict__ vb,
    const float* __restrict__ qpts, const float* __restrict__ kpts, const float* __restrict__ vpts,
    ushort_t* __restrict__ catb)
{
    const int node = blockIdx.x;
    const int b = node >> 11;
    const int tid = threadIdx.x;
    const int lane = tid & 63;
    const int wv = tid >> 6;

    __shared__ ushort_t s_hEb[KK * DD];   // 7680 B
    __shared__ float s_cat[1088];
    __shared__ float s_qp[96];
    __shared__ float s_p[HH][32];
    __shared__ int   s_j[32];
    __shared__ float s_mask[32];
    __shared__ float s_opt[48];

    if (tid < 96) s_qp[tid] = qpts[(size_t)node * 96 + tid];
    if (tid < KK) {
        s_j[tid] = Eidx[(size_t)node * KK + tid];
        s_mask[tid] = 100000.0f * (mask_att[(size_t)node * KK + tid] - 1.0f);
    }
    __syncthreads();

    const int h = wv;
    const int l32 = lane & 31;
    const int g = lane >> 5;
    const float* hE_node = hE + (size_t)node * (KK * DD);

    const unsigned qu0 = *(const unsigned*)&qb[(size_t)node * 512 + h * DD + 2 * l32];
    const unsigned qu1 = *(const unsigned*)&qb[(size_t)node * 512 + h * DD + 64 + 2 * l32];
    const float q0 = bflo(qu0), q1 = bfhi(qu0), q2 = bflo(qu1), q3 = bfhi(qu1);
    const float wb0 = Wb[(l32 +  0) * HH + h];
    const float wb1 = Wb[(l32 + 32) * HH + h];
    const float wb2 = Wb[(l32 + 64) * HH + h];
    const float wb3 = Wb[(l32 + 96) * HH + h];
    const float cpt = -0.5f * PT_SCALE * log1pf(expf(head_w[h]));
    const float bbh = INV3 * bb[h];
    const float qpl = (l32 < 24) ? s_qp[h * 24 + l32] : 0.f;

    // ---- logits: 3 chunks x 5 iters; 2 k's per iter (one per 32-lane group).
    // Load block: 10 scattered k-gathers + 5 kpts issued before any compute.
#define LPRE(K_, U0_, U1_, P_, I_) \
    const int K_ = ((c5 + I_) * 2) + g; \
    const size_t jb_##K_ = (size_t)(b * NN + s_j[K_]); \
    const unsigned U0_ = *(const unsigned*)&kb[jb_##K_ * 512 + h * DD + 2 * l32]; \
    const unsigned U1_ = *(const unsigned*)&kb[jb_##K_ * 512 + h * DD + 64 + 2 * l32]; \
    const float P_ = (l32 < 24) ? kpts[jb_##K_ * 96 + h * 24 + l32] : 0.f;

#define LCMP(K_, U0_, U1_, P_) { \
    const float* her = hE_node + K_ * DD; \
    float h0 = her[l32], h1 = her[l32 + 32], h2 = her[l32 + 64], h3 = her[l32 + 96]; \
    if (wv == 0) { \
        s_hEb[K_ * DD + l32]      = f2bf(h0); \
        s_hEb[K_ * DD + l32 + 32] = f2bf(h1); \
        s_hEb[K_ * DD + l32 + 64] = f2bf(h2); \
        s_hEb[K_ * DD + l32 + 96] = f2bf(h3); \
    } \
    float s = q0 * bflo(U0_) + q1 * bfhi(U0_) + q2 * bflo(U1_) + q3 * bfhi(U1_); \
    float t = wb0 * h0 + wb1 * h1 + wb2 * h2 + wb3 * h3; \
    float dd_ = qpl - P_; \
    float ptc = (l32 < 24) ? dd_ * dd_ : 0.f; \
    float val = INV3C * s + INV3 * t + cpt * ptc; \
    val += __shfl_down(val, 16, 32); \
    val += __shfl_down(val, 8, 32); \
    val += __shfl_down(val, 4, 32); \
    val += __shfl_down(val, 2, 32); \
    val += __shfl_down(val, 1, 32); \
    if (l32 == 0) s_p[h][K_] = val + bbh + s_mask[K_]; \
}

    #pragma unroll
    for (int c = 0; c < 3; ++c) {
        const int c5 = c * 5;
        LPRE(kA, uA0, uA1, pA, 0)
        LPRE(kB, uB0, uB1, pB, 1)
        LPRE(kC, uC0, uC1, pC, 2)
        LPRE(kD, uD0, uD1, pD, 3)
        LPRE(kE, uE0, uE1, pE, 4)
        LCMP(kA, uA0, uA1, pA)
        LCMP(kB, uB0, uB1, pB)
        LCMP(kC, uC0, uC1, pC)
        LCMP(kD, uD0, uD1, pD)
        LCMP(kE, uE0, uE1, pE)
    }
#undef LPRE
#undef LCMP
    __syncthreads();

    // ---- softmax over k ----
    {
        float v = (lane < KK) ? s_p[h][lane] : -INFINITY;
        float m = v;
        #pragma unroll
        for (int off = 16; off; off >>= 1) m = fmaxf(m, __shfl_down(m, off));
        m = __shfl(m, 0);
        float e = (lane < KK) ? expf(v - m) : 0.f;
        float s = e;
        #pragma unroll
        for (int off = 16; off; off >>= 1) s += __shfl_down(s, off);
        s = __shfl(s, 0);
        if (lane < KK) s_p[h][lane] = e / s;
    }
    __syncthreads();

    // ---- o + o_pair: 5 chunks x 6 named scattered v-gathers in flight ----
    {
        const int oh = tid >> 6;
        const int oc0 = (tid & 63) * 2;
        const ushort_t* vrow = vb + oh * DD + oc0;
        float a0 = 0.f, a1 = 0.f, b0 = 0.f, b1 = 0.f;
#define VLD(N_, I_) unsigned x##N_ = *(const unsigned*)(vrow + (size_t)(b * NN + s_j[(I_)]) * 512);
#define VCMP(N_, I_) { \
    float p = s_p[oh][(I_)]; \
    a0 = fmaf(p, bflo(x##N_), a0); a1 = fmaf(p, bfhi(x##N_), a1); \
    unsigned pe = *(const unsigned*)&s_hEb[(I_) * DD + oc0]; \
    b0 = fmaf(p, bflo(pe), b0); b1 = fmaf(p, bfhi(pe), b1); \
}
        #pragma unroll
        for (int c = 0; c < 5; ++c) {
            const int k6 = c * 6;
            VLD(0, k6 + 0)
            VLD(1, k6 + 1)
            VLD(2, k6 + 2)
            VLD(3, k6 + 3)
            VLD(4, k6 + 4)
            VLD(5, k6 + 5)
            VCMP(0, k6 + 0)
            VCMP(1, k6 + 1)
            VCMP(2, k6 + 2)
            VCMP(3, k6 + 3)
            VCMP(4, k6 + 4)
            VCMP(5, k6 + 5)
        }
#undef VLD
#undef VCMP
        s_cat[oh * DD + oc0]           = a0;
        s_cat[oh * DD + oc0 + 1]       = a1;
        s_cat[576 + oh * DD + oc0]     = b0;
        s_cat[576 + oh * DD + oc0 + 1] = b1;
    }
    // ---- o_pt: 48 threads, 5 chunks x 6 named loads ----
    if (tid < 48) {
        const int oh = (tid / 3) >> 2;
        float acc = 0.f;
        #pragma unroll
        for (int c = 0; c < 5; ++c) {
            const int k6 = c * 6;
            float f0 = vpts[(size_t)(b * NN + s_j[k6 + 0]) * 48 + tid];
            float f1 = vpts[(size_t)(b * NN + s_j[k6 + 1]) * 48 + tid];
            float f2 = vpts[(size_t)(b * NN + s_j[k6 + 2]) * 48 + tid];
            float f3 = vpts[(size_t)(b * NN + s_j[k6 + 3]) * 48 + tid];
            float f4 = vpts[(size_t)(b * NN + s_j[k6 + 4]) * 48 + tid];
            float f5 = vpts[(size_t)(b * NN + s_j[k6 + 5]) * 48 + tid];
            acc = fmaf(s_p[oh][k6 + 0], f0, acc);
            acc = fmaf(s_p[oh][k6 + 1], f1, acc);
            acc = fmaf(s_p[oh][k6 + 2], f2, acc);
            acc = fmaf(s_p[oh][k6 + 3], f3, acc);
            acc = fmaf(s_p[oh][k6 + 4], f4, acc);
            acc = fmaf(s_p[oh][k6 + 5], f5, acc);
        }
        s_opt[tid] = acc;
    }
    __syncthreads();
    if (tid < 16) {
        int jj = tid;
        float g0 = s_opt[jj * 3 + 0] - tvec[node * 3 + 0];
        float g1 = s_opt[jj * 3 + 1] - tvec[node * 3 + 1];
        float g2 = s_opt[jj * 3 + 2] - tvec[node * 3 + 2];
        float l0 = R[node * 9 + 0] * g0 + R[node * 9 + 3] * g1 + R[node * 9 + 6] * g2;
        float l1 = R[node * 9 + 1] * g0 + R[node * 9 + 4] * g1 + R[node * 9 + 7] * g2;
        float l2 = R[node * 9 + 2] * g0 + R[node * 9 + 5] * g1 + R[node * 9 + 8] * g2;
        s_cat[512 + 0 * 16 + jj] = l0;
        s_cat[512 + 1 * 16 + jj] = l1;
        s_cat[512 + 2 * 16 + jj] = l2;
        s_cat[560 + jj] = sqrtf(l0 * l0 + l1 * l1 + l2 * l2 + 1e-8f);
    }
    __syncthreads();

    for (int i = tid; i < 1088; i += 256)
        catb[(size_t)node * 1088 + i] = f2bf(s_cat[i]);
}

// ---- tail: MFMA GEMMs. 16 nodes/block, 512 threads (8 waves), grid 256. ----
__global__ __launch_bounds__(512) void tail_kernel(
    const float* __restrict__ hV, const float* __restrict__ maskV,
    const ushort_t* __restrict__ catb,
    const ushort_t* __restrict__ WoutT, const float* __restrict__ bout,
    const float* __restrict__ ln0w, const float* __restrict__ ln0b,
    const float* __restrict__ ln1w, const float* __restrict__ ln1b,
    const ushort_t* __restrict__ Wm1T, const float* __restrict__ bm1,
    const ushort_t* __restrict__ Wm2T, const float* __restrict__ bm2,
    float* __restrict__ out)
{
    const int node0 = blockIdx.x * TM;
    const int tid = threadIdx.x;
    const int w  = tid >> 6;
    const int l  = tid & 63;
    const int lr = l & 15;
    const int lk = l >> 4;

    __shared__ float    s_x[TM][DD];
    __shared__ float    s_hv[TM][DD];
    __shared__ ushort_t s_hvb[TM][136];
    __shared__ ushort_t s_m1[TM][520];
    __shared__ float    s_rs[TM][16];
    __shared__ float    s_rq[TM][16];
    __shared__ float    s_stat[TM][2];

    // ---- GEMM1: s = cat[16x1088] @ Wout[1088x128]
    {
        f32x4 acc = {0.f, 0.f, 0.f, 0.f};
        const ushort_t* Ab = catb + (size_t)(node0 + lr) * 1088 + lk * 8;
        const ushort_t* Bb = WoutT + (size_t)(w * 16 + lr) * 1088 + lk * 8;
        #pragma unroll 2
        for (int ks = 0; ks < 34; ++ks) {
            short8 a = *(const short8*)(Ab + ks * 32);
            short8 bfr = *(const short8*)(Bb + ks * 32);
            acc = __builtin_amdgcn_mfma_f32_16x16x32_bf16(a, bfr, acc, 0, 0, 0);
        }
        #pragma unroll
        for (int i = 0; i < 4; ++i)
            s_x[lk * 4 + i][w * 16 + lr] = acc[i];
    }
    __syncthreads();

    // ---- bias + residual + LN0 ----
    if (tid < 256) {
        int r = tid >> 4, sg = tid & 15;
        float ss = 0.f, sq = 0.f;
        #pragma unroll
        for (int j = 0; j < 8; ++j) {
            int cc = sg * 8 + j;
            float x = s_x[r][cc] + bout[cc] + hV[(size_t)(node0 + r) * DD + cc];
            s_x[r][cc] = x;
            ss += x; sq += x * x;
        }
        s_rs[r][sg] = ss; s_rq[r][sg] = sq;
    }
    __syncthreads();
    if (tid < TM) {
        float ss = 0.f, sq = 0.f;
        #pragma unroll
        for (int sg = 0; sg < 16; ++sg) { ss += s_rs[tid][sg]; sq += s_rq[tid][sg]; }
        float mu = ss / 128.f;
        s_stat[tid][0] = mu;
        s_stat[tid][1] = rsqrtf(sq / 128.f - mu * mu + 1e-5f);
    }
    __syncthreads();
    {
        int idx = tid * 4;
        int r = idx >> 7, cc = idx & 127;
        float mu = s_stat[r][0], rstd = s_stat[r][1];
        #pragma unroll
        for (int j = 0; j < 4; ++j) {
            float hvv = (s_x[r][cc + j] - mu) * rstd * ln0w[cc + j] + ln0b[cc + j];
            s_hv[r][cc + j] = hvv;
            s_hvb[r][cc + j] = f2bf(hvv);
        }
    }
    __syncthreads();

    // ---- GEMM2: m1 = hv[16x128] @ Wm1[128x512], ReLU ----
    {
        const ushort_t* Ab = &s_hvb[lr][lk * 8];
        #pragma unroll
        for (int t = 0; t < 4; ++t) {
            int n0 = w * 64 + t * 16;
            f32x4 acc = {0.f, 0.f, 0.f, 0.f};
            const ushort_t* Bb = Wm1T + (size_t)(n0 + lr) * 128 + lk * 8;
            #pragma unroll
            for (int ks = 0; ks < 4; ++ks) {
                short8 a = *(const short8*)(Ab + ks * 32);
                short8 bfr = *(const short8*)(Bb + ks * 32);
                acc = __builtin_amdgcn_mfma_f32_16x16x32_bf16(a, bfr, acc, 0, 0, 0);
            }
            int n = n0 + lr;
            float bm = bm1[n];
            #pragma unroll
            for (int i = 0; i < 4; ++i)
                s_m1[lk * 4 + i][n] = f2bf(fmaxf(acc[i] + bm, 0.f));
        }
    }
    __syncthreads();

    // ---- GEMM3: m = m1[16x512] @ Wm2[512x128] ----
    {
        f32x4 acc = {0.f, 0.f, 0.f, 0.f};
        const ushort_t* Ab = &s_m1[lr][lk * 8];
        const ushort_t* Bb = Wm2T + (size_t)(w * 16 + lr) * 512 + lk * 8;
        #pragma unroll 4
        for (int ks = 0; ks < 16; ++ks) {
            short8 a = *(const short8*)(Ab + ks * 32);
            short8 bfr = *(const short8*)(Bb + ks * 32);
            acc = __builtin_amdgcn_mfma_f32_16x16x32_bf16(a, bfr, acc, 0, 0, 0);
        }
        #pragma unroll
        for (int i = 0; i < 4; ++i)
            s_x[lk * 4 + i][w * 16 + lr] = acc[i];
    }
    __syncthreads();

    // ---- bm2 + residual + LN1 ----
    if (tid < 256) {
        int r = tid >> 4, sg = tid & 15;
        float ss = 0.f, sq = 0.f;
        #pragma unroll
        for (int j = 0; j < 8; ++j) {
            int cc = sg * 8 + j;
            float x = s_x[r][cc] + bm2[cc] + s_hv[r][cc];
            s_x[r][cc] = x;
            ss += x; sq += x * x;
        }
        s_rs[r][sg] = ss; s_rq[r][sg] = sq;
    }
    __syncthreads();
    if (tid < TM) {
        float ss = 0.f, sq = 0.f;
        #pragma unroll
        for (int sg = 0; sg < 16; ++sg) { ss += s_rs[tid][sg]; sq += s_rq[tid][sg]; }
        float mu = ss / 128.f;
        s_stat[tid][0] = mu;
        s_stat[tid][1] = rsqrtf(sq / 128.f - mu * mu + 1e-5f);
    }
    __syncthreads();
    {
        int idx = tid * 4;
        int r = idx >> 7, cc = idx & 127;
        float mu = s_stat[r][0], rstd = s_stat[r][1];
        float mk = maskV[node0 + r];
        float4 o;
        o.x = ((s_x[r][cc + 0] - mu) * rstd * ln1w[cc + 0] + ln1b[cc + 0]) * mk;
        o.y = ((s_x[r][cc + 1] - mu) * rstd * ln1w[cc + 1] + ln1b[cc + 1]) * mk;
        o.z = ((s_x[r][cc + 2] - mu) * rstd * ln1w[cc + 2] + ln1b[cc + 2]) * mk;
        o.w = ((s_x[r][cc + 3] - mu) * rstd * ln1w[cc + 3] + ln1b[cc + 3]) * mk;
        *(float4*)&out[(size_t)(node0 + r) * DD + cc] = o;
    }
}

extern "C" void kernel_launch(void* const* d_in, const int* in_sizes, int n_in,
                              void* d_out, int out_size, void* d_ws, size_t ws_size,
                              hipStream_t stream)
{
    const float* hV      = (const float*)d_in[0];
    const float* hE      = (const float*)d_in[1];
    const int*   Eidx    = (const int*)  d_in[2];
    const float* R       = (const float*)d_in[3];
    const float* tvec    = (const float*)d_in[4];
    const float* mask_at = (const float*)d_in[5];
    const float* maskV   = (const float*)d_in[6];
    const float* Wq      = (const float*)d_in[7];
    const float* bq      = (const float*)d_in[8];
    const float* Wkv     = (const float*)d_in[9];
    const float* bkv     = (const float*)d_in[10];
    const float* Wqp     = (const float*)d_in[11];
    const float* bqp     = (const float*)d_in[12];
    const float* Wkvp    = (const float*)d_in[13];
    const float* bkvp    = (const float*)d_in[14];
    const float* Wb      = (const float*)d_in[15];
    const float* bb      = (const float*)d_in[16];
    const float* hw      = (const float*)d_in[17];
    const float* Wout    = (const float*)d_in[18];
    const float* bout    = (const float*)d_in[19];
    const float* ln0w    = (const float*)d_in[20];
    const float* ln0b    = (const float*)d_in[21];
    const float* ln1w    = (const float*)d_in[22];
    const float* ln1b    = (const float*)d_in[23];
    const float* Wm1     = (const float*)d_in[24];
    const float* bm1     = (const float*)d_in[25];
    const float* Wm2     = (const float*)d_in[26];
    const float* bm2     = (const float*)d_in[27];

    const size_t nodes = (size_t)BB * NN;
    ushort_t* qb     = (ushort_t*)d_ws;                 // nodes*512 bf16
    ushort_t* kb     = qb + nodes * 512;
    ushort_t* vb     = kb + nodes * 512;
    ushort_t* catb   = vb + nodes * 512;                // nodes*1088
    ushort_t* WoutT  = catb + nodes * 1088;
    ushort_t* Wm1T   = WoutT + 128 * 1088;
    ushort_t* Wm2T   = Wm1T + 512 * 128;
    ushort_t* WprojT = Wm2T + 128 * 512;                // 1792*128
    float* qpts = (float*)(WprojT + 1792 * 128);
    float* kpts = qpts + nodes * 96;
    float* vpts = kpts + nodes * 96;

    prep_kernel<<<256, 256, 0, stream>>>(Wout, Wm1, Wm2, Wq, Wkv, Wqp, Wkvp,
                                         WoutT, Wm1T, Wm2T, WprojT);

    proj_kernel<<<(int)(nodes / TM) * 2, 512, 0, stream>>>(
        hV, R, tvec, WprojT, bq, bkv, bqp, bkvp,
        qb, kb, vb, qpts, kpts, vpts);

    attn_kernel<<<(int)nodes, 256, 0, stream>>>(
        hE, Eidx, R, tvec, mask_at,
        Wb, bb, hw,
        qb, kb, vb, qpts, kpts, vpts, catb);

    tail_kernel<<<(int)(nodes / TM), 512, 0, stream>>>(
        hV, maskV, catb,
        WoutT, bout, ln0w, ln0b, ln1w, ln1b,
        Wm1T, bm1, Wm2T, bm2, (float*)d_out);
}

// Round 13
// 104.914 us; speedup vs baseline: 1.5660x; 1.0169x over previous
//
#include <hip/hip_runtime.h>
#include <math.h>

#define BB 2
#define NN 2048
#define KK 30
#define DD 128
#define HH 4
#define PQ_ 8
#define PV_ 4
#define TM 16      // nodes per MFMA block (proj + tail)

#define INV3C    0.05103103630798288f   // sqrt(1/(3*128))
#define INV3     0.5773502691896258f    // sqrt(1/3)
#define PT_SCALE 0.09622504486493764f   // sqrt(1/108)

typedef __attribute__((ext_vector_type(8))) short short8;
typedef __attribute__((ext_vector_type(4))) float f32x4;
typedef unsigned short ushort_t;

__device__ __forceinline__ ushort_t f2bf(float f) {
    unsigned u = __float_as_uint(f);
    unsigned r = u + 0x7FFFu + ((u >> 16) & 1u);   // RNE
    return (ushort_t)(r >> 16);
}
__device__ __forceinline__ float bf2f(ushort_t u) {
    return __uint_as_float(((unsigned)u) << 16);
}
__device__ __forceinline__ float bflo(unsigned u) {
    return __uint_as_float(u << 16);
}
__device__ __forceinline__ float bfhi(unsigned u) {
    return __uint_as_float(u & 0xffff0000u);
}

// ---- weight prep: bf16 transposed weights for all MFMA GEMMs ----
__global__ __launch_bounds__(256) void prep_kernel(
    const float* __restrict__ Wout, const float* __restrict__ Wm1,
    const float* __restrict__ Wm2,
    const float* __restrict__ Wq, const float* __restrict__ Wkv,
    const float* __restrict__ Wqp, const float* __restrict__ Wkvp,
    ushort_t* __restrict__ WoutT, ushort_t* __restrict__ Wm1T,
    ushort_t* __restrict__ Wm2T, ushort_t* __restrict__ WprojT)
{
    const int stride = gridDim.x * blockDim.x;
    const int t0 = blockIdx.x * blockDim.x + threadIdx.x;
    for (int idx = t0; idx < 128 * 1088; idx += stride) {
        int n = idx / 1088, k = idx - n * 1088;
        WoutT[idx] = f2bf(Wout[(size_t)k * 128 + n]);
    }
    for (int idx = t0; idx < 512 * 128; idx += stride) {
        int n = idx >> 7, k = idx & 127;
        Wm1T[idx] = f2bf(Wm1[(size_t)k * 512 + n]);
    }
    for (int idx = t0; idx < 128 * 512; idx += stride) {
        int n = idx >> 9, k = idx & 511;
        Wm2T[idx] = f2bf(Wm2[(size_t)k * 128 + n]);
    }
    // fused proj weight: n<512 q | 512..1536 kv | 1536..1632 qp | 1632..1776 kvp | pad
    for (int idx = t0; idx < 1792 * 128; idx += stride) {
        int n = idx >> 7, k = idx & 127;
        float v;
        if (n < 512)       v = Wq[(size_t)k * 512 + n];
        else if (n < 1536) v = Wkv[(size_t)k * 1024 + (n - 512)];
        else if (n < 1632) v = Wqp[k * 96 + (n - 1536)];
        else if (n < 1776) v = Wkvp[k * 144 + (n - 1632)];
        else               v = 0.f;
        WprojT[idx] = f2bf(v);
    }
}

// ---- proj: MFMA GEMM X[16x128]bf16 @ WprojT ----
__global__ __launch_bounds__(512) void proj_kernel(
    const float* __restrict__ hV, const float* __restrict__ R, const float* __restrict__ tvec,
    const ushort_t* __restrict__ WT,
    const float* __restrict__ bq, const float* __restrict__ bkv,
    const float* __restrict__ bqp, const float* __restrict__ bkvp,
    ushort_t* __restrict__ qb, ushort_t* __restrict__ kb, ushort_t* __restrict__ vb,
    float* __restrict__ qpts, float* __restrict__ kpts, float* __restrict__ vpts)
{
    const int node0 = (blockIdx.x >> 1) * TM;
    const int half  = blockIdx.x & 1;
    const int tid = threadIdx.x;
    const int w = tid >> 6, l = tid & 63, lr = l & 15, lk = l >> 4;

    __shared__ ushort_t s_A[TM][128];    // 4 KB bf16 A tile
    __shared__ float s_qp[TM][96];       // 6 KB
    __shared__ float s_kvp[TM][144];     // 9 KB

    {
        int i = tid * 4; int r = i >> 7, c = i & 127;
        float4 x = *(const float4*)&hV[(size_t)(node0 + r) * DD + c];
        s_A[r][c + 0] = f2bf(x.x); s_A[r][c + 1] = f2bf(x.y);
        s_A[r][c + 2] = f2bf(x.z); s_A[r][c + 3] = f2bf(x.w);
    }
    __syncthreads();

    const ushort_t* Ab = &s_A[lr][lk * 8];
    for (int t = 0; t < 7; ++t) {
        const int tile = half * 56 + w * 7 + t;
        const int n = tile * 16 + lr;
        f32x4 acc = {0.f, 0.f, 0.f, 0.f};
        const ushort_t* Bb = WT + (size_t)n * 128 + lk * 8;
        #pragma unroll
        for (int ks = 0; ks < 4; ++ks) {
            short8 a = *(const short8*)(Ab + ks * 32);
            short8 bfr = *(const short8*)(Bb + ks * 32);
            acc = __builtin_amdgcn_mfma_f32_16x16x32_bf16(a, bfr, acc, 0, 0, 0);
        }
        if (n < 512) {
            float bias = bq[n];
            #pragma unroll
            for (int i = 0; i < 4; ++i)
                qb[(size_t)(node0 + lk * 4 + i) * 512 + n] = f2bf(acc[i] + bias);
        } else if (n < 1536) {
            int n2 = n - 512;
            float bias = bkv[n2];
            int hh = n2 >> 8, wcol = n2 & 255;
            ushort_t* base = (wcol < 128) ? kb : vb;
            int off = hh * DD + (wcol & 127);
            #pragma unroll
            for (int i = 0; i < 4; ++i)
                base[(size_t)(node0 + lk * 4 + i) * 512 + off] = f2bf(acc[i] + bias);
        } else if (n < 1632) {
            int c = n - 1536;
            float bias = bqp[c];
            #pragma unroll
            for (int i = 0; i < 4; ++i) s_qp[lk * 4 + i][c] = acc[i] + bias;
        } else if (n < 1776) {
            int c = n - 1632;
            float bias = bkvp[c];
            #pragma unroll
            for (int i = 0; i < 4; ++i) s_kvp[lk * 4 + i][c] = acc[i] + bias;
        }
    }
    __syncthreads();

    if (half == 1) {
        for (int idx = tid; idx < TM * 96; idx += 512) {
            int r = idx / 96, u = idx % 96;
            int j = u / 3, d = u % 3;
            int node = node0 + r;
            float acc = tvec[node * 3 + d];
            #pragma unroll
            for (int y = 0; y < 3; ++y)
                acc = fmaf(R[node * 9 + d * 3 + y], s_qp[r][y * 32 + j], acc);
            qpts[(size_t)node * 96 + j * 3 + d] = acc;
        }
        for (int idx = tid; idx < TM * 144; idx += 512) {
            int r = idx / 144, u = idx % 144;
            int jj = u / 3, d = u % 3;
            int node = node0 + r;
            float acc = tvec[node * 3 + d];
            #pragma unroll
            for (int y = 0; y < 3; ++y)
                acc = fmaf(R[node * 9 + d * 3 + y], s_kvp[r][y * 48 + jj], acc);
            int hh = jj / 12, pp = jj % 12;
            if (pp < PQ_) kpts[(size_t)node * 96 + (hh * PQ_ + pp) * 3 + d] = acc;
            else          vpts[(size_t)node * 48 + (hh * PV_ + (pp - PQ_)) * 3 + d] = acc;
        }
    }
}

// ---- attn core: r10 structure + cooperative hE pre-stage (the one change).
// hE hits HBM once per block via coalesced float4; logits loop is pure
// L2-gather + LDS. launch_bounds(256,8) for full wave occupancy. ----
__global__ __launch_bounds__(256, 8) void attn_kernel(
    const float* __restrict__ hE, const int* __restrict__ Eidx,
    const float* __restrict__ R, const float* __restrict__ tvec,
    const float* __restrict__ mask_att,
    const float* __restrict__ Wb, const float* __restrict__ bb,
    const float* __restrict__ head_w,
    const ushort_t* __restrict__ qb, const ushort_t* __restrict__ kb,
    const ushort_t* __restrict__ vb,
    const float* __restrict__ qpts, const float* __restrict__ kpts, const float* __restrict__ vpts,
    ushort_t* __restrict__ catb)
{
    const int node = blockIdx.x;
    const int b = node >> 11;
    const int tid = threadIdx.x;
    const int lane = tid & 63;
    const int wv = tid >> 6;

    __shared__ ushort_t s_hEb[KK * DD];   // 7680 B
    __shared__ float s_cat[1088];
    __shared__ float s_qp[96];
    __shared__ float s_p[HH][32];
    __shared__ int   s_j[32];
    __shared__ float s_mask[32];
    __shared__ float s_opt[48];

    if (tid < 96) s_qp[tid] = qpts[(size_t)node * 96 + tid];
    if (tid < KK) {
        s_j[tid] = Eidx[(size_t)node * KK + tid];
        s_mask[tid] = 100000.0f * (mask_att[(size_t)node * KK + tid] - 1.0f);
    }
    // ---- cooperative hE pre-stage: 960 float4, coalesced, fp32 -> bf16 LDS
    {
        const float4* src = (const float4*)(hE + (size_t)node * (KK * DD));
        #pragma unroll
        for (int i = 0; i < 4; ++i) {
            const int idx = tid + i * 256;
            if (idx < 960) {
                float4 x = src[idx];
                unsigned lo = ((unsigned)f2bf(x.y) << 16) | (unsigned)f2bf(x.x);
                unsigned hi = ((unsigned)f2bf(x.w) << 16) | (unsigned)f2bf(x.z);
                *(unsigned*)&s_hEb[idx * 4]     = lo;
                *(unsigned*)&s_hEb[idx * 4 + 2] = hi;
            }
        }
    }
    __syncthreads();

    const int h = wv;
    const int l32 = lane & 31;
    const int g = lane >> 5;

    const unsigned qu0 = *(const unsigned*)&qb[(size_t)node * 512 + h * DD + 2 * l32];
    const unsigned qu1 = *(const unsigned*)&qb[(size_t)node * 512 + h * DD + 64 + 2 * l32];
    const float q0 = bflo(qu0), q1 = bfhi(qu0), q2 = bflo(qu1), q3 = bfhi(qu1);
    const float wb0 = Wb[(2 * l32 +  0) * HH + h];
    const float wb1 = Wb[(2 * l32 +  1) * HH + h];
    const float wb2 = Wb[(2 * l32 + 64) * HH + h];
    const float wb3 = Wb[(2 * l32 + 65) * HH + h];
    const float cpt = -0.5f * PT_SCALE * log1pf(expf(head_w[h]));
    const float bbh = INV3 * bb[h];
    const float qpl = (l32 < 24) ? s_qp[h * 24 + l32] : 0.f;

    // ---- logits: 2 k's per iteration; k from gather, hE from LDS ----
    #pragma unroll
    for (int kx2 = 0; kx2 < KK / 2; ++kx2) {
        const int k = kx2 * 2 + g;
        size_t jb = (size_t)(b * NN + s_j[k]);
        const ushort_t* kr = kb + jb * 512 + h * DD;
        unsigned ku0 = *(const unsigned*)&kr[2 * l32];
        unsigned ku1 = *(const unsigned*)&kr[64 + 2 * l32];
        unsigned eu0 = *(const unsigned*)&s_hEb[k * DD + 2 * l32];
        unsigned eu1 = *(const unsigned*)&s_hEb[k * DD + 64 + 2 * l32];
        float s = q0 * bflo(ku0) + q1 * bfhi(ku0) + q2 * bflo(ku1) + q3 * bfhi(ku1);
        float t = wb0 * bflo(eu0) + wb1 * bfhi(eu0) + wb2 * bflo(eu1) + wb3 * bfhi(eu1);
        float ptc = 0.f;
        if (l32 < 24) {
            float d = qpl - kpts[jb * 96 + h * 24 + l32];
            ptc = d * d;
        }
        float val = INV3C * s + INV3 * t + cpt * ptc;
        #pragma unroll
        for (int off = 16; off; off >>= 1) val += __shfl_down(val, off, 32);
        if (l32 == 0) s_p[h][k] = val + bbh + s_mask[k];
    }
    __syncthreads();

    // ---- softmax over k ----
    {
        float v = (lane < KK) ? s_p[h][lane] : -INFINITY;
        float m = v;
        #pragma unroll
        for (int off = 16; off; off >>= 1) m = fmaxf(m, __shfl_down(m, off));
        m = __shfl(m, 0);
        float e = (lane < KK) ? expf(v - m) : 0.f;
        float s = e;
        #pragma unroll
        for (int off = 16; off; off >>= 1) s += __shfl_down(s, off);
        s = __shfl(s, 0);
        if (lane < KK) s_p[h][lane] = e / s;
    }
    __syncthreads();

    // ---- o (bf16 gathered v) + o_pair (LDS hE), fully unrolled ----
    {
        const int oh = tid >> 6;
        const int oc0 = (tid & 63) * 2;
        const ushort_t* vrow = vb + oh * DD + oc0;
        float a0 = 0.f, a1 = 0.f, b0 = 0.f, b1 = 0.f;
        #pragma unroll
        for (int kx = 0; kx < KK; ++kx) {
            unsigned pv = *(const unsigned*)(vrow + (size_t)(b * NN + s_j[kx]) * 512);
            unsigned pe = *(const unsigned*)&s_hEb[kx * DD + oc0];
            float p = s_p[oh][kx];
            a0 = fmaf(p, bflo(pv), a0);
            a1 = fmaf(p, bfhi(pv), a1);
            b0 = fmaf(p, bflo(pe), b0);
            b1 = fmaf(p, bfhi(pe), b1);
        }
        s_cat[oh * DD + oc0]           = a0;
        s_cat[oh * DD + oc0 + 1]       = a1;
        s_cat[576 + oh * DD + oc0]     = b0;
        s_cat[576 + oh * DD + oc0 + 1] = b1;
    }
    // ---- o_pt: 48 items, fully unrolled ----
    if (tid < 48) {
        const int oh = (tid / 3) >> 2;
        float acc = 0.f;
        #pragma unroll
        for (int kx = 0; kx < KK; ++kx)
            acc = fmaf(s_p[oh][kx], vpts[(size_t)(b * NN + s_j[kx]) * 48 + tid], acc);
        s_opt[tid] = acc;
    }
    __syncthreads();
    if (tid < 16) {
        int jj = tid;
        float g0 = s_opt[jj * 3 + 0] - tvec[node * 3 + 0];
        float g1 = s_opt[jj * 3 + 1] - tvec[node * 3 + 1];
        float g2 = s_opt[jj * 3 + 2] - tvec[node * 3 + 2];
        float l0 = R[node * 9 + 0] * g0 + R[node * 9 + 3] * g1 + R[node * 9 + 6] * g2;
        float l1 = R[node * 9 + 1] * g0 + R[node * 9 + 4] * g1 + R[node * 9 + 7] * g2;
        float l2 = R[node * 9 + 2] * g0 + R[node * 9 + 5] * g1 + R[node * 9 + 8] * g2;
        s_cat[512 + 0 * 16 + jj] = l0;
        s_cat[512 + 1 * 16 + jj] = l1;
        s_cat[512 + 2 * 16 + jj] = l2;
        s_cat[560 + jj] = sqrtf(l0 * l0 + l1 * l1 + l2 * l2 + 1e-8f);
    }
    __syncthreads();

    for (int i = tid; i < 1088; i += 256)
        catb[(size_t)node * 1088 + i] = f2bf(s_cat[i]);
}

// ---- tail: MFMA GEMMs. 16 nodes/block, 512 threads (8 waves), grid 256. ----
__global__ __launch_bounds__(512) void tail_kernel(
    const float* __restrict__ hV, const float* __restrict__ maskV,
    const ushort_t* __restrict__ catb,
    const ushort_t* __restrict__ WoutT, const float* __restrict__ bout,
    const float* __restrict__ ln0w, const float* __restrict__ ln0b,
    const float* __restrict__ ln1w, const float* __restrict__ ln1b,
    const ushort_t* __restrict__ Wm1T, const float* __restrict__ bm1,
    const ushort_t* __restrict__ Wm2T, const float* __restrict__ bm2,
    float* __restrict__ out)
{
    const int node0 = blockIdx.x * TM;
    const int tid = threadIdx.x;
    const int w  = tid >> 6;
    const int l  = tid & 63;
    const int lr = l & 15;
    const int lk = l >> 4;

    __shared__ float    s_x[TM][DD];
    __shared__ float    s_hv[TM][DD];
    __shared__ ushort_t s_hvb[TM][136];
    __shared__ ushort_t s_m1[TM][520];
    __shared__ float    s_rs[TM][16];
    __shared__ float    s_rq[TM][16];
    __shared__ float    s_stat[TM][2];

    // ---- GEMM1: s = cat[16x1088] @ Wout[1088x128]
    {
        f32x4 acc = {0.f, 0.f, 0.f, 0.f};
        const ushort_t* Ab = catb + (size_t)(node0 + lr) * 1088 + lk * 8;
        const ushort_t* Bb = WoutT + (size_t)(w * 16 + lr) * 1088 + lk * 8;
        #pragma unroll 2
        for (int ks = 0; ks < 34; ++ks) {
            short8 a = *(const short8*)(Ab + ks * 32);
            short8 bfr = *(const short8*)(Bb + ks * 32);
            acc = __builtin_amdgcn_mfma_f32_16x16x32_bf16(a, bfr, acc, 0, 0, 0);
        }
        #pragma unroll
        for (int i = 0; i < 4; ++i)
            s_x[lk * 4 + i][w * 16 + lr] = acc[i];
    }
    __syncthreads();

    // ---- bias + residual + LN0 ----
    if (tid < 256) {
        int r = tid >> 4, sg = tid & 15;
        float ss = 0.f, sq = 0.f;
        #pragma unroll
        for (int j = 0; j < 8; ++j) {
            int cc = sg * 8 + j;
            float x = s_x[r][cc] + bout[cc] + hV[(size_t)(node0 + r) * DD + cc];
            s_x[r][cc] = x;
            ss += x; sq += x * x;
        }
        s_rs[r][sg] = ss; s_rq[r][sg] = sq;
    }
    __syncthreads();
    if (tid < TM) {
        float ss = 0.f, sq = 0.f;
        #pragma unroll
        for (int sg = 0; sg < 16; ++sg) { ss += s_rs[tid][sg]; sq += s_rq[tid][sg]; }
        float mu = ss / 128.f;
        s_stat[tid][0] = mu;
        s_stat[tid][1] = rsqrtf(sq / 128.f - mu * mu + 1e-5f);
    }
    __syncthreads();
    {
        int idx = tid * 4;
        int r = idx >> 7, cc = idx & 127;
        float mu = s_stat[r][0], rstd = s_stat[r][1];
        #pragma unroll
        for (int j = 0; j < 4; ++j) {
            float hvv = (s_x[r][cc + j] - mu) * rstd * ln0w[cc + j] + ln0b[cc + j];
            s_hv[r][cc + j] = hvv;
            s_hvb[r][cc + j] = f2bf(hvv);
        }
    }
    __syncthreads();

    // ---- GEMM2: m1 = hv[16x128] @ Wm1[128x512], ReLU ----
    {
        const ushort_t* Ab = &s_hvb[lr][lk * 8];
        #pragma unroll
        for (int t = 0; t < 4; ++t) {
            int n0 = w * 64 + t * 16;
            f32x4 acc = {0.f, 0.f, 0.f, 0.f};
            const ushort_t* Bb = Wm1T + (size_t)(n0 + lr) * 128 + lk * 8;
            #pragma unroll
            for (int ks = 0; ks < 4; ++ks) {
                short8 a = *(const short8*)(Ab + ks * 32);
                short8 bfr = *(const short8*)(Bb + ks * 32);
                acc = __builtin_amdgcn_mfma_f32_16x16x32_bf16(a, bfr, acc, 0, 0, 0);
            }
            int n = n0 + lr;
            float bm = bm1[n];
            #pragma unroll
            for (int i = 0; i < 4; ++i)
                s_m1[lk * 4 + i][n] = f2bf(fmaxf(acc[i] + bm, 0.f));
        }
    }
    __syncthreads();

    // ---- GEMM3: m = m1[16x512] @ Wm2[512x128] ----
    {
        f32x4 acc = {0.f, 0.f, 0.f, 0.f};
        const ushort_t* Ab = &s_m1[lr][lk * 8];
        const ushort_t* Bb = Wm2T + (size_t)(w * 16 + lr) * 512 + lk * 8;
        #pragma unroll 4
        for (int ks = 0; ks < 16; ++ks) {
            short8 a = *(const short8*)(Ab + ks * 32);
            short8 bfr = *(const short8*)(Bb + ks * 32);
            acc = __builtin_amdgcn_mfma_f32_16x16x32_bf16(a, bfr, acc, 0, 0, 0);
        }
        #pragma unroll
        for (int i = 0; i < 4; ++i)
            s_x[lk * 4 + i][w * 16 + lr] = acc[i];
    }
    __syncthreads();

    // ---- bm2 + residual + LN1 ----
    if (tid < 256) {
        int r = tid >> 4, sg = tid & 15;
        float ss = 0.f, sq = 0.f;
        #pragma unroll
        for (int j = 0; j < 8; ++j) {
            int cc = sg * 8 + j;
            float x = s_x[r][cc] + bm2[cc] + s_hv[r][cc];
            s_x[r][cc] = x;
            ss += x; sq += x * x;
        }
        s_rs[r][sg] = ss; s_rq[r][sg] = sq;
    }
    __syncthreads();
    if (tid < TM) {
        float ss = 0.f, sq = 0.f;
        #pragma unroll
        for (int sg = 0; sg < 16; ++sg) { ss += s_rs[tid][sg]; sq += s_rq[tid][sg]; }
        float mu = ss / 128.f;
        s_stat[tid][0] = mu;
        s_stat[tid][1] = rsqrtf(sq / 128.f - mu * mu + 1e-5f);
    }
    __syncthreads();
    {
        int idx = tid * 4;
        int r = idx >> 7, cc = idx & 127;
        float mu = s_stat[r][0], rstd = s_stat[r][1];
        float mk = maskV[node0 + r];
        float4 o;
        o.x = ((s_x[r][cc + 0] - mu) * rstd * ln1w[cc + 0] + ln1b[cc + 0]) * mk;
        o.y = ((s_x[r][cc + 1] - mu) * rstd * ln1w[cc + 1] + ln1b[cc + 1]) * mk;
        o.z = ((s_x[r][cc + 2] - mu) * rstd * ln1w[cc + 2] + ln1b[cc + 2]) * mk;
        o.w = ((s_x[r][cc + 3] - mu) * rstd * ln1w[cc + 3] + ln1b[cc + 3]) * mk;
        *(float4*)&out[(size_t)(node0 + r) * DD + cc] = o;
    }
}

extern "C" void kernel_launch(void* const* d_in, const int* in_sizes, int n_in,
                              void* d_out, int out_size, void* d_ws, size_t ws_size,
                              hipStream_t stream)
{
    const float* hV      = (const float*)d_in[0];
    const float* hE      = (const float*)d_in[1];
    const int*   Eidx    = (const int*)  d_in[2];
    const float* R       = (const float*)d_in[3];
    const float* tvec    = (const float*)d_in[4];
    const float* mask_at = (const float*)d_in[5];
    const float* maskV   = (const float*)d_in[6];
    const float* Wq      = (const float*)d_in[7];
    const float* bq      = (const float*)d_in[8];
    const float* Wkv     = (const float*)d_in[9];
    const float* bkv     = (const float*)d_in[10];
    const float* Wqp     = (const float*)d_in[11];
    const float* bqp     = (const float*)d_in[12];
    const float* Wkvp    = (const float*)d_in[13];
    const float* bkvp    = (const float*)d_in[14];
    const float* Wb      = (const float*)d_in[15];
    const float* bb      = (const float*)d_in[16];
    const float* hw      = (const float*)d_in[17];
    const float* Wout    = (const float*)d_in[18];
    const float* bout    = (const float*)d_in[19];
    const float* ln0w    = (const float*)d_in[20];
    const float* ln0b    = (const float*)d_in[21];
    const float* ln1w    = (const float*)d_in[22];
    const float* ln1b    = (const float*)d_in[23];
    const float* Wm1     = (const float*)d_in[24];
    const float* bm1     = (const float*)d_in[25];
    const float* Wm2     = (const float*)d_in[26];
    const float* bm2     = (const float*)d_in[27];

    const size_t nodes = (size_t)BB * NN;
    ushort_t* qb     = (ushort_t*)d_ws;                 // nodes*512 bf16
    ushort_t* kb     = qb + nodes * 512;
    ushort_t* vb     = kb + nodes * 512;
    ushort_t* catb   = vb + nodes * 512;                // nodes*1088
    ushort_t* WoutT  = catb + nodes * 1088;
    ushort_t* Wm1T   = WoutT + 128 * 1088;
    ushort_t* Wm2T   = Wm1T + 512 * 128;
    ushort_t* WprojT = Wm2T + 128 * 512;                // 1792*128
    float* qpts = (float*)(WprojT + 1792 * 128);
    float* kpts = qpts + nodes * 96;
    float* vpts = kpts + nodes * 96;

    prep_kernel<<<256, 256, 0, stream>>>(Wout, Wm1, Wm2, Wq, Wkv, Wqp, Wkvp,
                                         WoutT, Wm1T, Wm2T, WprojT);

    proj_kernel<<<(int)(nodes / TM) * 2, 512, 0, stream>>>(
        hV, R, tvec, WprojT, bq, bkv, bqp, bkvp,
        qb, kb, vb, qpts, kpts, vpts);

    attn_kernel<<<(int)nodes, 256, 0, stream>>>(
        hE, Eidx, R, tvec, mask_at,
        Wb, bb, hw,
        qb, kb, vb, qpts, kpts, vpts, catb);

    tail_kernel<<<(int)(nodes / TM), 512, 0, stream>>>(
        hV, maskV, catb,
        WoutT, bout, ln0w, ln0b, ln1w, ln1b,
        Wm1T, bm1, Wm2T, bm2, (float*)d_out);
}